// Round 1
// baseline (368.943 us; speedup 1.0000x reference)
//
#include <hip/hip_runtime.h>

#define SEQ_LEN 16384
#define DIM 128
#define NH 256
#define NB 32
#define TOPK 8

// Kernel 1: mask_penalty[n] = mean over batch of mask[b][n]
__global__ void penalty_kernel(const float* __restrict__ mask, float* __restrict__ pen) {
    int n = blockIdx.x * blockDim.x + threadIdx.x;
    if (n < SEQ_LEN) {
        float s = 0.f;
        #pragma unroll
        for (int b = 0; b < NB; ++b) s += mask[(size_t)b * SEQ_LEN + n];
        pen[n] = s * (1.0f / NB);
    }
}

// Kernel 2: one block = 256 threads (4 waves). Thread t register-caches hyper row t.
// Each grid-stride iteration processes a group of 4 node rows:
//   Phase A: thread t computes sim for (4 rows) x (hyperedge t), stores to LDS.
//   Phase B: wave w owns row w of the group (4 values/lane), does softmax pieces +
//            ballot-binary-search top-8 selection + threshold, writes binary output.
__global__ __launch_bounds__(256, 2)
void hyper_kernel(const float* __restrict__ pen, const float* __restrict__ node,
                  const float* __restrict__ hyper, float* __restrict__ out) {
    const int tid  = threadIdx.x;
    const int lane = tid & 63;
    const int wv   = tid >> 6;
    __shared__ __align__(16) float sv[4][NH];

    // register-cache this thread's hyperedge row (h == tid): 32 float4 = 128 VGPRs
    float4 hc[DIM / 4];
    {
        const float4* h4 = (const float4*)(hyper + (size_t)tid * DIM);
        #pragma unroll
        for (int i = 0; i < DIM / 4; ++i) hc[i] = h4[i];
    }

    const int ngroups = SEQ_LEN / 4;
    for (int g = blockIdx.x; g < ngroups; g += gridDim.x) {
        const int r0 = g * 4;
        const float4* n4 = (const float4*)(node + (size_t)r0 * DIM); // block-uniform

        float a0 = 0.f, a1 = 0.f, a2 = 0.f, a3 = 0.f;
        #pragma unroll
        for (int i = 0; i < DIM / 4; ++i) {
            const float4 hv = hc[i];
            const float4 x0 = n4[i];
            const float4 x1 = n4[(DIM / 4) + i];
            const float4 x2 = n4[2 * (DIM / 4) + i];
            const float4 x3 = n4[3 * (DIM / 4) + i];
            a0 = fmaf(x0.x, hv.x, a0); a0 = fmaf(x0.y, hv.y, a0);
            a0 = fmaf(x0.z, hv.z, a0); a0 = fmaf(x0.w, hv.w, a0);
            a1 = fmaf(x1.x, hv.x, a1); a1 = fmaf(x1.y, hv.y, a1);
            a1 = fmaf(x1.z, hv.z, a1); a1 = fmaf(x1.w, hv.w, a1);
            a2 = fmaf(x2.x, hv.x, a2); a2 = fmaf(x2.y, hv.y, a2);
            a2 = fmaf(x2.z, hv.z, a2); a2 = fmaf(x2.w, hv.w, a2);
            a3 = fmaf(x3.x, hv.x, a3); a3 = fmaf(x3.y, hv.y, a3);
            a3 = fmaf(x3.z, hv.z, a3); a3 = fmaf(x3.w, hv.w, a3);
        }
        // sim = relu(alpha*sim) * penalty[row]   (alpha = 1)
        const float v0 = fmaxf(a0, 0.f) * pen[r0];
        const float v1 = fmaxf(a1, 0.f) * pen[r0 + 1];
        const float v2 = fmaxf(a2, 0.f) * pen[r0 + 2];
        const float v3 = fmaxf(a3, 0.f) * pen[r0 + 3];

        __syncthreads();                 // protect sv reuse from previous group
        sv[0][tid] = v0;
        sv[1][tid] = v1;
        sv[2][tid] = v2;
        sv[3][tid] = v3;
        __syncthreads();

        // -------- Phase B: wave wv handles row (r0 + wv); h = 4*lane + j --------
        const float4 vvv = *(const float4*)&sv[wv][lane << 2];
        const float b0 = vvv.x, b1 = vvv.y, b2 = vvv.z, b3 = vvv.w;

        // row max (for stable softmax, matches jax.nn.softmax)
        float m = fmaxf(fmaxf(b0, b1), fmaxf(b2, b3));
        #pragma unroll
        for (int off = 32; off >= 1; off >>= 1) m = fmaxf(m, __shfl_xor(m, off, 64));

        const float e0 = expf(b0 - m), e1 = expf(b1 - m);
        const float e2 = expf(b2 - m), e3 = expf(b3 - m);
        float z = e0 + e1 + e2 + e3;
        #pragma unroll
        for (int off = 32; off >= 1; off >>= 1) z += __shfl_xor(z, off, 64);

        // binary search (on float bit patterns; all v >= 0 so bits are monotone)
        // for t = bits(8th-largest value): max t with count(v >= t) >= 8
        const unsigned u0 = __float_as_uint(b0), u1 = __float_as_uint(b1);
        const unsigned u2 = __float_as_uint(b2), u3 = __float_as_uint(b3);
        unsigned t = 0u;
        for (int bit = 30; bit >= 0; --bit) {
            const unsigned cand = t | (1u << bit);
            const int c = __popcll(__ballot(u0 >= cand)) + __popcll(__ballot(u1 >= cand))
                        + __popcll(__ballot(u2 >= cand)) + __popcll(__ballot(u3 >= cand));
            if (c >= TOPK) t = cand;
        }
        // tie resolution: jax.lax.top_k takes lowest indices first among equal values
        const int cgt = __popcll(__ballot(u0 > t)) + __popcll(__ballot(u1 > t))
                      + __popcll(__ballot(u2 > t)) + __popcll(__ballot(u3 > t));
        const int need = TOPK - cgt;  // slots left for values tied with the 8th
        const unsigned long long q0 = __ballot(u0 == t), q1 = __ballot(u1 == t);
        const unsigned long long q2 = __ballot(u2 == t), q3 = __ballot(u3 == t);
        const unsigned long long lt = (1ull << lane) - 1ull; // lanes below (h-major order)
        const int base = __popcll(q0 & lt) + __popcll(q1 & lt)
                       + __popcll(q2 & lt) + __popcll(q3 & lt);
        const int rk0 = base;
        const int rk1 = rk0 + (u0 == t ? 1 : 0);
        const int rk2 = rk1 + (u1 == t ? 1 : 0);
        const int rk3 = rk2 + (u2 == t ? 1 : 0);

        // threshold: softmax p > 0.001  <=>  e > 0.001 * z
        const float zth = 0.001f * z;
        const bool s0 = ((u0 > t) || ((u0 == t) && rk0 < need)) && (e0 > zth);
        const bool s1 = ((u1 > t) || ((u1 == t) && rk1 < need)) && (e1 > zth);
        const bool s2 = ((u2 > t) || ((u2 == t) && rk2 < need)) && (e2 > zth);
        const bool s3 = ((u3 > t) || ((u3 == t) && rk3 < need)) && (e3 > zth);

        float4 o;
        o.x = s0 ? 1.f : 0.f;
        o.y = s1 ? 1.f : 0.f;
        o.z = s2 ? 1.f : 0.f;
        o.w = s3 ? 1.f : 0.f;
        *(float4*)(out + (size_t)(r0 + wv) * NH + (lane << 2)) = o;
    }
}

extern "C" void kernel_launch(void* const* d_in, const int* in_sizes, int n_in,
                              void* d_out, int out_size, void* d_ws, size_t ws_size,
                              hipStream_t stream) {
    // inputs: 0=features (unused), 1=mask [B,SEQ], 2=node_embeds [SEQ,D], 3=hyper_embeds [H,D]
    const float* mask  = (const float*)d_in[1];
    const float* node  = (const float*)d_in[2];
    const float* hyper = (const float*)d_in[3];
    float* pen = (float*)d_ws;          // SEQ_LEN floats of scratch
    float* out = (float*)d_out;

    penalty_kernel<<<SEQ_LEN / 256, 256, 0, stream>>>(mask, pen);
    hyper_kernel<<<512, 256, 0, stream>>>(pen, node, hyper, out);
}

// Round 2
// 367.695 us; speedup vs baseline: 1.0034x; 1.0034x over previous
//
#include <hip/hip_runtime.h>

#define SEQ_LEN 16384
#define DIM 128
#define NH 256
#define NB 32
#define TOPK 8

// One fused kernel. Block = 256 threads (4 waves). Thread t register-caches
// hyper row t (32 x float4 = 128 VGPRs). Grid-stride over groups of 4 node rows:
//   Phase A: thread t computes relu(dot(node_row_j, hyper_t)) for j=0..3 -> LDS.
//   Phase B: wave w owns row w of the group. It computes the row's mask penalty
//            (lanes 0..31 gather mask[b][row], butterfly sum), scales, then does
//            softmax stats + ballot-binary-search top-8 + threshold, and writes
//            the binary row (float4 per lane, coalesced).
__global__ __launch_bounds__(256, 2)
void hyper_kernel(const float* __restrict__ mask, const float* __restrict__ node,
                  const float* __restrict__ hyper, float* __restrict__ out) {
    const int tid  = threadIdx.x;
    const int lane = tid & 63;
    const int wv   = tid >> 6;
    __shared__ __align__(16) float sv[4][NH];

    // register-cache this thread's hyperedge row (h == tid)
    float4 hc[DIM / 4];
    {
        const float4* h4 = (const float4*)(hyper + (size_t)tid * DIM);
        #pragma unroll
        for (int i = 0; i < DIM / 4; ++i) hc[i] = h4[i];
    }

    const int ngroups = SEQ_LEN / 4;
    for (int g = blockIdx.x; g < ngroups; g += gridDim.x) {
        const int r0  = g * 4;
        const int row = r0 + wv;                  // row owned by this wave in Phase B
        const float4* n4 = (const float4*)(node + (size_t)r0 * DIM); // block-uniform

        float a0 = 0.f, a1 = 0.f, a2 = 0.f, a3 = 0.f;
        #pragma unroll
        for (int i = 0; i < DIM / 4; ++i) {
            const float4 hv = hc[i];
            const float4 x0 = n4[i];
            const float4 x1 = n4[(DIM / 4) + i];
            const float4 x2 = n4[2 * (DIM / 4) + i];
            const float4 x3 = n4[3 * (DIM / 4) + i];
            a0 = fmaf(x0.x, hv.x, a0); a0 = fmaf(x0.y, hv.y, a0);
            a0 = fmaf(x0.z, hv.z, a0); a0 = fmaf(x0.w, hv.w, a0);
            a1 = fmaf(x1.x, hv.x, a1); a1 = fmaf(x1.y, hv.y, a1);
            a1 = fmaf(x1.z, hv.z, a1); a1 = fmaf(x1.w, hv.w, a1);
            a2 = fmaf(x2.x, hv.x, a2); a2 = fmaf(x2.y, hv.y, a2);
            a2 = fmaf(x2.z, hv.z, a2); a2 = fmaf(x2.w, hv.w, a2);
            a3 = fmaf(x3.x, hv.x, a3); a3 = fmaf(x3.y, hv.y, a3);
            a3 = fmaf(x3.z, hv.z, a3); a3 = fmaf(x3.w, hv.w, a3);
        }

        __syncthreads();                 // protect sv reuse from previous group
        sv[0][tid] = fmaxf(a0, 0.f);     // relu(alpha*sim), unscaled
        sv[1][tid] = fmaxf(a1, 0.f);
        sv[2][tid] = fmaxf(a2, 0.f);
        sv[3][tid] = fmaxf(a3, 0.f);
        // issue the penalty gather now; its latency overlaps the barrier wait
        const float mv = (lane < NB) ? mask[(size_t)lane * SEQ_LEN + row] : 0.f;
        __syncthreads();

        // -------- Phase B: wave wv handles `row`; h = 4*lane + j --------
        // penalty = mean over batch of mask[:, row]
        float p = mv;
        #pragma unroll
        for (int off = 32; off >= 1; off >>= 1) p += __shfl_xor(p, off, 64);
        p *= (1.0f / NB);

        const float4 vvv = *(const float4*)&sv[wv][lane << 2];
        const float b0 = vvv.x * p, b1 = vvv.y * p;
        const float b2 = vvv.z * p, b3 = vvv.w * p;

        // row max (stable softmax, matches jax.nn.softmax)
        float m = fmaxf(fmaxf(b0, b1), fmaxf(b2, b3));
        #pragma unroll
        for (int off = 32; off >= 1; off >>= 1) m = fmaxf(m, __shfl_xor(m, off, 64));

        const float e0 = expf(b0 - m), e1 = expf(b1 - m);
        const float e2 = expf(b2 - m), e3 = expf(b3 - m);
        float z = e0 + e1 + e2 + e3;
        #pragma unroll
        for (int off = 32; off >= 1; off >>= 1) z += __shfl_xor(z, off, 64);

        // binary search on float bit patterns (all v >= 0 so bits are monotone)
        // for t = bits(8th-largest value): max t with count(v >= t) >= 8
        const unsigned u0 = __float_as_uint(b0), u1 = __float_as_uint(b1);
        const unsigned u2 = __float_as_uint(b2), u3 = __float_as_uint(b3);
        unsigned t = 0u;
        for (int bit = 30; bit >= 0; --bit) {
            const unsigned cand = t | (1u << bit);
            const int c = __popcll(__ballot(u0 >= cand)) + __popcll(__ballot(u1 >= cand))
                        + __popcll(__ballot(u2 >= cand)) + __popcll(__ballot(u3 >= cand));
            if (c >= TOPK) t = cand;
        }
        // tie resolution: jax.lax.top_k takes lowest indices first among equal values
        const int cgt = __popcll(__ballot(u0 > t)) + __popcll(__ballot(u1 > t))
                      + __popcll(__ballot(u2 > t)) + __popcll(__ballot(u3 > t));
        const int need = TOPK - cgt;
        const unsigned long long q0 = __ballot(u0 == t), q1 = __ballot(u1 == t);
        const unsigned long long q2 = __ballot(u2 == t), q3 = __ballot(u3 == t);
        const unsigned long long lt = (1ull << lane) - 1ull; // lanes below (h-major order)
        const int base = __popcll(q0 & lt) + __popcll(q1 & lt)
                       + __popcll(q2 & lt) + __popcll(q3 & lt);
        const int rk0 = base;
        const int rk1 = rk0 + (u0 == t ? 1 : 0);
        const int rk2 = rk1 + (u1 == t ? 1 : 0);
        const int rk3 = rk2 + (u2 == t ? 1 : 0);

        // threshold: softmax p > 0.001  <=>  e > 0.001 * z
        const float zth = 0.001f * z;
        const bool s0 = ((u0 > t) || ((u0 == t) && rk0 < need)) && (e0 > zth);
        const bool s1 = ((u1 > t) || ((u1 == t) && rk1 < need)) && (e1 > zth);
        const bool s2 = ((u2 > t) || ((u2 == t) && rk2 < need)) && (e2 > zth);
        const bool s3 = ((u3 > t) || ((u3 == t) && rk3 < need)) && (e3 > zth);

        float4 o;
        o.x = s0 ? 1.f : 0.f;
        o.y = s1 ? 1.f : 0.f;
        o.z = s2 ? 1.f : 0.f;
        o.w = s3 ? 1.f : 0.f;
        *(float4*)(out + (size_t)row * NH + (lane << 2)) = o;
    }
}

extern "C" void kernel_launch(void* const* d_in, const int* in_sizes, int n_in,
                              void* d_out, int out_size, void* d_ws, size_t ws_size,
                              hipStream_t stream) {
    // inputs: 0=features (unused), 1=mask [B,SEQ], 2=node_embeds [SEQ,D], 3=hyper_embeds [H,D]
    const float* mask  = (const float*)d_in[1];
    const float* node  = (const float*)d_in[2];
    const float* hyper = (const float*)d_in[3];
    float* out = (float*)d_out;

    hyper_kernel<<<512, 256, 0, stream>>>(mask, node, hyper, out);
}